// Round 1
// baseline (1800.497 us; speedup 1.0000x reference)
//
#include <hip/hip_runtime.h>

// Res_MCNN_branch2: conv(3->20,7x7)+relu+pool -> conv(20->40,5x5)+relu+pool
//                   -> conv(40->20,5x5)+relu -> conv(20->10,5x5)+relu
//                   -> conv(10->1,1x1) + relu(gray_resized), relu.
// All fp32 direct convolutions, LDS input tiling, per-wave oc-groups so
// weight reads are scalar (s_load). Bilinear resize of gray == 2x2 average
// at rows {4i+1,4i+2} x cols {4j+1,4j+2} (exact for the 4x scale factor).

#define IN_H 768
#define IN_W 1024
#define P1_H 384
#define P1_W 512
#define P2_H 192
#define P2_W 256

// ---------------- conv1 (3->20, 7x7, pad 3) + relu + maxpool2 ----------------
// pooled tile 32x4 per block -> conv region 64x8 -> input region 70x14 (LDS stride 72)
// 256 threads: 64 spatial (4 conv cols x 2 conv rows each) x 4 oc-groups of 5.
__global__ __launch_bounds__(256) void conv1_pool(
    const float* __restrict__ in, const float* __restrict__ w,
    const float* __restrict__ bias, float* __restrict__ P1)
{
  __shared__ __align__(16) float lds[3][14][72];
  const int b = blockIdx.z, bx = blockIdx.x, by = blockIdx.y;
  const int tid = threadIdx.x;
  const int in_r0 = by * 8 - 3;
  const int in_c0 = bx * 64 - 3;
  for (int i = tid; i < 3 * 14 * 70; i += 256) {
    int c = i / (14 * 70);
    int rem = i % (14 * 70);
    int r = rem / 70, cc = rem % 70;
    int gr = in_r0 + r, gc = in_c0 + cc;
    float v = 0.f;
    if (gr >= 0 && gr < IN_H && gc >= 0 && gc < IN_W)
      v = in[(((size_t)b * 3 + c) * IN_H + gr) * IN_W + gc];
    lds[c][r][cc] = v;
  }
  __syncthreads();
  const int s = tid & 63;
  const int och = __builtin_amdgcn_readfirstlane(tid >> 6);  // 0..3, wave-uniform
  const int sx = s & 15;   // conv cols 4sx..4sx+3
  const int sy = s >> 4;   // pooled row in tile; conv rows 2sy, 2sy+1
  float acc[5][8];
  #pragma unroll
  for (int o = 0; o < 5; ++o)
    #pragma unroll
    for (int k = 0; k < 8; ++k) acc[o][k] = 0.f;

  for (int c = 0; c < 3; ++c) {
    #pragma unroll
    for (int ky = 0; ky < 7; ++ky) {
      const float* r0p = &lds[c][2 * sy + ky][4 * sx];
      const float* r1p = r0p + 72;
      float4 a0 = *(const float4*)(r0p);
      float4 a1 = *(const float4*)(r0p + 4);
      float4 a2 = *(const float4*)(r0p + 8);
      float4 d0 = *(const float4*)(r1p);
      float4 d1 = *(const float4*)(r1p + 4);
      float4 d2 = *(const float4*)(r1p + 8);
      float rr0[12] = {a0.x,a0.y,a0.z,a0.w, a1.x,a1.y,a1.z,a1.w, a2.x,a2.y,a2.z,a2.w};
      float rr1[12] = {d0.x,d0.y,d0.z,d0.w, d1.x,d1.y,d1.z,d1.w, d2.x,d2.y,d2.z,d2.w};
      #pragma unroll
      for (int o = 0; o < 5; ++o) {
        const int oc = och * 5 + o;
        const float* wp = w + ((oc * 3 + c) * 7 + ky) * 7;
        #pragma unroll
        for (int kx = 0; kx < 7; ++kx) {
          const float wv = wp[kx];
          acc[o][0] += wv * rr0[kx];     acc[o][1] += wv * rr0[kx + 1];
          acc[o][2] += wv * rr0[kx + 2]; acc[o][3] += wv * rr0[kx + 3];
          acc[o][4] += wv * rr1[kx];     acc[o][5] += wv * rr1[kx + 1];
          acc[o][6] += wv * rr1[kx + 2]; acc[o][7] += wv * rr1[kx + 3];
        }
      }
    }
  }
  const int PR = by * 4 + sy;
  const int PC = bx * 32 + 2 * sx;
  #pragma unroll
  for (int o = 0; o < 5; ++o) {
    const int oc = och * 5 + o;
    const float bv = bias[oc];
    float p0 = fmaxf(fmaxf(acc[o][0], acc[o][1]), fmaxf(acc[o][4], acc[o][5])) + bv;
    float p1 = fmaxf(fmaxf(acc[o][2], acc[o][3]), fmaxf(acc[o][6], acc[o][7])) + bv;
    float2 st = make_float2(fmaxf(p0, 0.f), fmaxf(p1, 0.f));
    *(float2*)&P1[(((size_t)b * 20 + oc) * P1_H + PR) * P1_W + PC] = st;
  }
}

// ---------------- conv2 (20->40, 5x5, pad 2) + relu + maxpool2 ----------------
// pooled tile 32x4 -> conv 64x8 -> input 68x12 x 20ch (LDS stride 68, 65,280 B)
// 512 threads: 64 spatial x 8 oc-groups of 5.
__global__ __launch_bounds__(512) void conv2_pool(
    const float* __restrict__ P1, const float* __restrict__ w,
    const float* __restrict__ bias, float* __restrict__ P2)
{
  __shared__ __align__(16) float lds[20][12][68];
  const int b = blockIdx.z, bx = blockIdx.x, by = blockIdx.y;
  const int tid = threadIdx.x;
  const int in_r0 = by * 8 - 2;
  const int in_c0 = bx * 64 - 2;
  for (int i = tid; i < 20 * 12 * 68; i += 512) {
    int c = i / (12 * 68);
    int rem = i % (12 * 68);
    int r = rem / 68, cc = rem % 68;
    int gr = in_r0 + r, gc = in_c0 + cc;
    float v = 0.f;
    if (gr >= 0 && gr < P1_H && gc >= 0 && gc < P1_W)
      v = P1[(((size_t)b * 20 + c) * P1_H + gr) * P1_W + gc];
    lds[c][r][cc] = v;
  }
  __syncthreads();
  const int s = tid & 63;
  const int och = __builtin_amdgcn_readfirstlane(tid >> 6);  // 0..7
  const int sx = s & 15;
  const int sy = s >> 4;
  float acc[5][8];
  #pragma unroll
  for (int o = 0; o < 5; ++o)
    #pragma unroll
    for (int k = 0; k < 8; ++k) acc[o][k] = 0.f;

  for (int c = 0; c < 20; ++c) {
    #pragma unroll
    for (int ky = 0; ky < 5; ++ky) {
      const float* r0p = &lds[c][2 * sy + ky][4 * sx];
      const float* r1p = r0p + 68;
      float4 a0 = *(const float4*)(r0p);
      float4 a1 = *(const float4*)(r0p + 4);
      float4 d0 = *(const float4*)(r1p);
      float4 d1 = *(const float4*)(r1p + 4);
      float rr0[8] = {a0.x,a0.y,a0.z,a0.w, a1.x,a1.y,a1.z,a1.w};
      float rr1[8] = {d0.x,d0.y,d0.z,d0.w, d1.x,d1.y,d1.z,d1.w};
      #pragma unroll
      for (int o = 0; o < 5; ++o) {
        const int oc = och * 5 + o;
        const float* wp = w + ((oc * 20 + c) * 5 + ky) * 5;
        #pragma unroll
        for (int kx = 0; kx < 5; ++kx) {
          const float wv = wp[kx];
          acc[o][0] += wv * rr0[kx];     acc[o][1] += wv * rr0[kx + 1];
          acc[o][2] += wv * rr0[kx + 2]; acc[o][3] += wv * rr0[kx + 3];
          acc[o][4] += wv * rr1[kx];     acc[o][5] += wv * rr1[kx + 1];
          acc[o][6] += wv * rr1[kx + 2]; acc[o][7] += wv * rr1[kx + 3];
        }
      }
    }
  }
  const int PR = by * 4 + sy;
  const int PC = bx * 32 + 2 * sx;
  #pragma unroll
  for (int o = 0; o < 5; ++o) {
    const int oc = och * 5 + o;
    const float bv = bias[oc];
    float p0 = fmaxf(fmaxf(acc[o][0], acc[o][1]), fmaxf(acc[o][4], acc[o][5])) + bv;
    float p1 = fmaxf(fmaxf(acc[o][2], acc[o][3]), fmaxf(acc[o][6], acc[o][7])) + bv;
    float2 st = make_float2(fmaxf(p0, 0.f), fmaxf(p1, 0.f));
    *(float2*)&P2[(((size_t)b * 40 + oc) * P2_H + PR) * P2_W + PC] = st;
  }
}

// ---------------- conv3 (40->20, 5x5, pad 2) + relu ----------------
// out tile 32x8 -> input 36x12 per channel (LDS stride 36); 2 chunks of 20 ic.
// 256 threads: 64 spatial (4 cols x 1 row) x 4 oc-groups of 5.
__global__ __launch_bounds__(256) void conv3_relu(
    const float* __restrict__ P2, const float* __restrict__ w,
    const float* __restrict__ bias, float* __restrict__ X3)
{
  __shared__ __align__(16) float lds[20][12][36];
  const int b = blockIdx.z, bx = blockIdx.x, by = blockIdx.y;
  const int tid = threadIdx.x;
  const int in_r0 = by * 8 - 2, in_c0 = bx * 32 - 2;
  const int s = tid & 63;
  const int och = __builtin_amdgcn_readfirstlane(tid >> 6);  // 0..3
  const int sx = s & 7, sy = s >> 3;
  float acc[5][4];
  #pragma unroll
  for (int o = 0; o < 5; ++o)
    #pragma unroll
    for (int k = 0; k < 4; ++k) acc[o][k] = 0.f;

  for (int chunk = 0; chunk < 2; ++chunk) {
    __syncthreads();
    for (int i = tid; i < 20 * 12 * 36; i += 256) {
      int c = i / (12 * 36);
      int rem = i % (12 * 36);
      int r = rem / 36, cc = rem % 36;
      int gr = in_r0 + r, gc = in_c0 + cc;
      float v = 0.f;
      if (gr >= 0 && gr < P2_H && gc >= 0 && gc < P2_W)
        v = P2[(((size_t)b * 40 + chunk * 20 + c) * P2_H + gr) * P2_W + gc];
      lds[c][r][cc] = v;
    }
    __syncthreads();
    for (int c = 0; c < 20; ++c) {
      #pragma unroll
      for (int ky = 0; ky < 5; ++ky) {
        const float* rp = &lds[c][sy + ky][4 * sx];
        float4 a0 = *(const float4*)(rp);
        float4 a1 = *(const float4*)(rp + 4);
        float rr[8] = {a0.x,a0.y,a0.z,a0.w, a1.x,a1.y,a1.z,a1.w};
        #pragma unroll
        for (int o = 0; o < 5; ++o) {
          const int oc = och * 5 + o;
          const float* wp = w + ((oc * 40 + chunk * 20 + c) * 5 + ky) * 5;
          #pragma unroll
          for (int kx = 0; kx < 5; ++kx) {
            const float wv = wp[kx];
            acc[o][0] += wv * rr[kx];     acc[o][1] += wv * rr[kx + 1];
            acc[o][2] += wv * rr[kx + 2]; acc[o][3] += wv * rr[kx + 3];
          }
        }
      }
    }
  }
  const int OR = by * 8 + sy, OC = bx * 32 + 4 * sx;
  #pragma unroll
  for (int o = 0; o < 5; ++o) {
    const int oc = och * 5 + o;
    const float bv = bias[oc];
    float4 st;
    st.x = fmaxf(acc[o][0] + bv, 0.f);
    st.y = fmaxf(acc[o][1] + bv, 0.f);
    st.z = fmaxf(acc[o][2] + bv, 0.f);
    st.w = fmaxf(acc[o][3] + bv, 0.f);
    *(float4*)&X3[(((size_t)b * 20 + oc) * P2_H + OR) * P2_W + OC] = st;
  }
}

// ---------------- conv4 (20->10, 5x5, pad 2) + relu ----------------
// out tile 32x8 -> input 36x12 x 20ch; 128 threads: 64 spatial x 2 oc-groups of 5.
__global__ __launch_bounds__(128) void conv4_relu(
    const float* __restrict__ X3, const float* __restrict__ w,
    const float* __restrict__ bias, float* __restrict__ X4)
{
  __shared__ __align__(16) float lds[20][12][36];
  const int b = blockIdx.z, bx = blockIdx.x, by = blockIdx.y;
  const int tid = threadIdx.x;
  const int in_r0 = by * 8 - 2, in_c0 = bx * 32 - 2;
  for (int i = tid; i < 20 * 12 * 36; i += 128) {
    int c = i / (12 * 36);
    int rem = i % (12 * 36);
    int r = rem / 36, cc = rem % 36;
    int gr = in_r0 + r, gc = in_c0 + cc;
    float v = 0.f;
    if (gr >= 0 && gr < P2_H && gc >= 0 && gc < P2_W)
      v = X3[(((size_t)b * 20 + c) * P2_H + gr) * P2_W + gc];
    lds[c][r][cc] = v;
  }
  __syncthreads();
  const int s = tid & 63;
  const int och = __builtin_amdgcn_readfirstlane(tid >> 6);  // 0..1
  const int sx = s & 7, sy = s >> 3;
  float acc[5][4];
  #pragma unroll
  for (int o = 0; o < 5; ++o)
    #pragma unroll
    for (int k = 0; k < 4; ++k) acc[o][k] = 0.f;

  for (int c = 0; c < 20; ++c) {
    #pragma unroll
    for (int ky = 0; ky < 5; ++ky) {
      const float* rp = &lds[c][sy + ky][4 * sx];
      float4 a0 = *(const float4*)(rp);
      float4 a1 = *(const float4*)(rp + 4);
      float rr[8] = {a0.x,a0.y,a0.z,a0.w, a1.x,a1.y,a1.z,a1.w};
      #pragma unroll
      for (int o = 0; o < 5; ++o) {
        const int oc = och * 5 + o;
        const float* wp = w + ((oc * 20 + c) * 5 + ky) * 5;
        #pragma unroll
        for (int kx = 0; kx < 5; ++kx) {
          const float wv = wp[kx];
          acc[o][0] += wv * rr[kx];     acc[o][1] += wv * rr[kx + 1];
          acc[o][2] += wv * rr[kx + 2]; acc[o][3] += wv * rr[kx + 3];
        }
      }
    }
  }
  const int OR = by * 8 + sy, OC = bx * 32 + 4 * sx;
  #pragma unroll
  for (int o = 0; o < 5; ++o) {
    const int oc = och * 5 + o;
    const float bv = bias[oc];
    float4 st;
    st.x = fmaxf(acc[o][0] + bv, 0.f);
    st.y = fmaxf(acc[o][1] + bv, 0.f);
    st.z = fmaxf(acc[o][2] + bv, 0.f);
    st.w = fmaxf(acc[o][3] + bv, 0.f);
    *(float4*)&X4[(((size_t)b * 10 + oc) * P2_H + OR) * P2_W + OC] = st;
  }
}

// ---------------- conv5 (10->1, 1x1) + gray residual + relu ----------------
// bilinear 4x downsample == average of the 2x2 block at rows {4i+1,4i+2},
// cols {4j+1,4j+2} (exact: sample coords land at +1.5 with w=0.5).
__global__ __launch_bounds__(256) void conv5_res(
    const float* __restrict__ X4, const float* __restrict__ w5,
    const float* __restrict__ b5, const float* __restrict__ in,
    float* __restrict__ out)
{
  const int idx = blockIdx.x * 256 + threadIdx.x;  // 0 .. 8*192*256-1
  const int j = idx & 255;
  const int bi = idx >> 8;          // b*192 + i
  const int i = bi % 192;
  const int b = bi / 192;
  float sum = b5[0];
  #pragma unroll
  for (int c = 0; c < 10; ++c)
    sum += w5[c] * X4[(((size_t)b * 10 + c) * P2_H + i) * P2_W + j];
  const int r0 = 4 * i + 1, c0 = 4 * j + 1;
  float g = 0.f;
  #pragma unroll
  for (int ch = 0; ch < 3; ++ch) {
    const float coef = (ch == 0) ? 0.299f : ((ch == 1) ? 0.587f : 0.114f);
    const float* q = in + ((size_t)b * 3 + ch) * IN_H * IN_W;
    g += coef * (q[(size_t)r0 * IN_W + c0] + q[(size_t)r0 * IN_W + c0 + 1] +
                 q[(size_t)(r0 + 1) * IN_W + c0] + q[(size_t)(r0 + 1) * IN_W + c0 + 1]);
  }
  g *= 0.25f;
  out[idx] = fmaxf(sum + fmaxf(g, 0.f), 0.f);
}

extern "C" void kernel_launch(void* const* d_in, const int* in_sizes, int n_in,
                              void* d_out, int out_size, void* d_ws, size_t ws_size,
                              hipStream_t stream) {
  const float* input = (const float*)d_in[0];
  const float* w1 = (const float*)d_in[1];  const float* b1 = (const float*)d_in[2];
  const float* w2 = (const float*)d_in[3];  const float* b2 = (const float*)d_in[4];
  const float* w3 = (const float*)d_in[5];  const float* b3 = (const float*)d_in[6];
  const float* w4 = (const float*)d_in[7];  const float* b4 = (const float*)d_in[8];
  const float* w5 = (const float*)d_in[9];  const float* b5 = (const float*)d_in[10];
  float* out = (float*)d_out;
  char* ws = (char*)d_ws;

  // workspace layout (bytes):
  //   [0,            62,914,560)  P2  (8,40,192,256)
  //   [62,914,560,  188,743,680)  P1  (8,20,384,512); reused after conv2 as:
  //       X3 at P1 base      (8,20,192,256) = 31,457,280 B
  //       X4 at +31,457,280  (8,10,192,256) = 15,728,640 B
  float* P2 = (float*)ws;
  float* P1 = (float*)(ws + 62914560);
  float* X3 = P1;
  float* X4 = (float*)(ws + 62914560 + 31457280);

  conv1_pool<<<dim3(16, 96, 8), 256, 0, stream>>>(input, w1, b1, P1);
  conv2_pool<<<dim3(8, 48, 8), 512, 0, stream>>>(P1, w2, b2, P2);
  conv3_relu<<<dim3(8, 24, 8), 256, 0, stream>>>(P2, w3, b3, X3);
  conv4_relu<<<dim3(8, 24, 8), 128, 0, stream>>>(X3, w4, b4, X4);
  conv5_res<<<1536, 256, 0, stream>>>(X4, w5, b5, input, out);
}

// Round 2
// 1076.647 us; speedup vs baseline: 1.6723x; 1.6723x over previous
//
#include <hip/hip_runtime.h>

// Res_MCNN_branch2 on gfx950.
// conv1: fp32 direct (LDS tile) + relu + pool -> P1 f16 NHWC C=32 (20 real + 12 zero)
// conv2/3/4: implicit-GEMM f16 MFMA (16x16x32), NHWC, C padded to 32/64.
//   A = weights [tap][ocp][cp] (pre-packed f16), B = input tile in LDS,
//   D: col=lane&15 = pixel, row = quad*4+reg = oc.
// conv2 fuses relu+maxpool2 via shfl_xor; conv4 emits fp32 NHWC C=10.
// conv5: 1x1 conv + gray residual (bilinear 4x == 2x2 avg at rows/cols {4i+1,4i+2}).

typedef _Float16 half_t;
typedef _Float16 half8 __attribute__((ext_vector_type(8)));
typedef float floatx4 __attribute__((ext_vector_type(4)));

#define IN_H 768
#define IN_W 1024
#define P1H 384
#define P1W 512
#define P2H 192
#define P2W 256

// workspace offsets (bytes)
#define OFF_P2 0ULL                 // f16 [8][192][256][64]  = 50,331,648
#define OFF_P1 50331648ULL          // f16 [8][384][512][32]  = 100,663,296
#define OFF_X3 50331648ULL          // reuse P1 region after conv2
#define OFF_X4 0ULL                 // fp32 [8][192][256][10] reuse P2 region after conv3
#define OFF_W2 150994944ULL         // f16 [25][48][32] = 76,800
#define OFF_W3 151072768ULL         // f16 [25][32][64] = 102,400
#define OFF_W4 151175168ULL         // f16 [25][16][32] = 25,600

union PK4 { half_t h[4]; uint2 u; };

// ---------------- weight pre-pack (fp32 OIHW -> f16 [tap][ocp][cp]) ----------------
__global__ __launch_bounds__(256) void pack_weights(
    const float* __restrict__ w2, const float* __restrict__ w3,
    const float* __restrict__ w4,
    half_t* __restrict__ wp2, half_t* __restrict__ wp3, half_t* __restrict__ wp4)
{
  int t = blockIdx.x * 256 + threadIdx.x;
  if (t < 38400) {                       // conv2: [25][48][32]
    int tap = t / 1536, r = t % 1536, oc = r >> 5, c = r & 31;
    float v = (oc < 40 && c < 20) ? w2[(oc * 20 + c) * 25 + tap] : 0.f;
    wp2[t] = (half_t)v;
  } else if (t < 89600) {                // conv3: [25][32][64]
    int u = t - 38400;
    int tap = u / 2048, r = u % 2048, oc = r >> 6, c = r & 63;
    float v = (oc < 20 && c < 40) ? w3[(oc * 40 + c) * 25 + tap] : 0.f;
    wp3[u] = (half_t)v;
  } else if (t < 102400) {               // conv4: [25][16][32]
    int u = t - 89600;
    int tap = u / 512, r = u % 512, oc = r >> 5, c = r & 31;
    float v = (oc < 10 && c < 20) ? w4[(oc * 20 + c) * 25 + tap] : 0.f;
    wp4[u] = (half_t)v;
  }
}

// ---------------- conv1 (3->20, 7x7, pad 3) + relu + maxpool2 -> f16 NHWC32 ----------------
__global__ __launch_bounds__(256) void conv1_pool(
    const float* __restrict__ in, const float* __restrict__ w,
    const float* __restrict__ bias, half_t* __restrict__ P1)
{
  __shared__ __align__(16) float lds[3][14][72];
  const int b = blockIdx.z, bx = blockIdx.x, by = blockIdx.y;
  const int tid = threadIdx.x;
  const int in_r0 = by * 8 - 3;
  const int in_c0 = bx * 64 - 3;
  for (int i = tid; i < 3 * 14 * 70; i += 256) {
    int c = i / (14 * 70);
    int rem = i % (14 * 70);
    int r = rem / 70, cc = rem % 70;
    int gr = in_r0 + r, gc = in_c0 + cc;
    float v = 0.f;
    if (gr >= 0 && gr < IN_H && gc >= 0 && gc < IN_W)
      v = in[(((size_t)b * 3 + c) * IN_H + gr) * IN_W + gc];
    lds[c][r][cc] = v;
  }
  __syncthreads();
  const int s = tid & 63;
  const int och = __builtin_amdgcn_readfirstlane(tid >> 6);  // 0..3
  const int sx = s & 15;
  const int sy = s >> 4;
  float acc[5][8];
  #pragma unroll
  for (int o = 0; o < 5; ++o)
    #pragma unroll
    for (int k = 0; k < 8; ++k) acc[o][k] = 0.f;

  for (int c = 0; c < 3; ++c) {
    #pragma unroll
    for (int ky = 0; ky < 7; ++ky) {
      const float* r0p = &lds[c][2 * sy + ky][4 * sx];
      const float* r1p = r0p + 72;
      float4 a0 = *(const float4*)(r0p);
      float4 a1 = *(const float4*)(r0p + 4);
      float4 a2 = *(const float4*)(r0p + 8);
      float4 d0 = *(const float4*)(r1p);
      float4 d1 = *(const float4*)(r1p + 4);
      float4 d2 = *(const float4*)(r1p + 8);
      float rr0[12] = {a0.x,a0.y,a0.z,a0.w, a1.x,a1.y,a1.z,a1.w, a2.x,a2.y,a2.z,a2.w};
      float rr1[12] = {d0.x,d0.y,d0.z,d0.w, d1.x,d1.y,d1.z,d1.w, d2.x,d2.y,d2.z,d2.w};
      #pragma unroll
      for (int o = 0; o < 5; ++o) {
        const int oc = och * 5 + o;
        const float* wp = w + ((oc * 3 + c) * 7 + ky) * 7;
        #pragma unroll
        for (int kx = 0; kx < 7; ++kx) {
          const float wv = wp[kx];
          acc[o][0] += wv * rr0[kx];     acc[o][1] += wv * rr0[kx + 1];
          acc[o][2] += wv * rr0[kx + 2]; acc[o][3] += wv * rr0[kx + 3];
          acc[o][4] += wv * rr1[kx];     acc[o][5] += wv * rr1[kx + 1];
          acc[o][6] += wv * rr1[kx + 2]; acc[o][7] += wv * rr1[kx + 3];
        }
      }
    }
  }
  const int PR = by * 4 + sy;
  const int PC = bx * 32 + 2 * sx;
  half_t* P1p = P1 + (((size_t)b * P1H + PR) * P1W + PC) * 32;
  #pragma unroll
  for (int o = 0; o < 5; ++o) {
    const int oc = och * 5 + o;
    const float bv = bias[oc];
    float p0 = fmaxf(fmaxf(acc[o][0], acc[o][1]), fmaxf(acc[o][4], acc[o][5])) + bv;
    float p1 = fmaxf(fmaxf(acc[o][2], acc[o][3]), fmaxf(acc[o][6], acc[o][7])) + bv;
    P1p[oc]      = (half_t)fmaxf(p0, 0.f);
    P1p[32 + oc] = (half_t)fmaxf(p1, 0.f);
  }
  if (och == 3) {  // zero-fill padded channels 20..31 for both pixels
    *(uint2*)(P1p + 20) = make_uint2(0, 0);
    *(uint4*)(P1p + 24) = make_uint4(0, 0, 0, 0);
    *(uint2*)(P1p + 52) = make_uint2(0, 0);
    *(uint4*)(P1p + 56) = make_uint4(0, 0, 0, 0);
  }
}

// ---------------- conv2 (20->40, 5x5) MFMA + relu + pool -> P2 f16 NHWC64 ----------------
// conv tile 16x32 = 512 px (32 N-tiles); oc padded to 48 (3 M-tiles).
// wave: 8 N-tiles x 3 M-tiles = 24 MFMA per k-step; K = 25 taps x 32c.
__global__ __launch_bounds__(256) void conv2_mfma(
    const half_t* __restrict__ P1, const half_t* __restrict__ wp,
    const float* __restrict__ bias, half_t* __restrict__ P2)
{
  __shared__ __align__(16) half_t lin[20][36][32];   // 46080 B
  __shared__ __align__(16) half_t wlds[2][48][32];   // 6144 B
  const int b = blockIdx.z, ty0 = blockIdx.y * 16, tx0 = blockIdx.x * 32;
  const int tid = threadIdx.x;
  for (int i = tid; i < 2880; i += 256) {
    int px = i >> 2, part = i & 3;
    int row = px / 36, col = px - row * 36;
    int gy = ty0 - 2 + row, gx = tx0 - 2 + col;
    uint4 v = make_uint4(0, 0, 0, 0);
    if (gy >= 0 && gy < P1H && gx >= 0 && gx < P1W)
      v = *(const uint4*)(P1 + (((size_t)b * P1H + gy) * P1W + gx) * 32 + part * 8);
    *(uint4*)&lin[row][col][part * 8] = v;
  }
  if (tid < 192)
    *(uint4*)(&wlds[0][0][0] + tid * 8) = *(const uint4*)(wp + tid * 8);
  __syncthreads();

  const int wv = tid >> 6, ln = tid & 63, q = ln >> 4, nl = ln & 15;
  int baseB[8];
  #pragma unroll
  for (int j = 0; j < 8; ++j) {
    int nt = wv * 8 + j;
    int ly = (nt >> 2) * 2 + ((nl >> 1) & 1);
    int lx = (nt & 3) * 8 + (nl & 1) + ((nl >> 2) << 1);
    baseB[j] = (ly * 36 + lx) * 32 + q * 8;
  }
  const int aoff = nl * 32 + q * 8;
  floatx4 acc[3][8];
  #pragma unroll
  for (int mt = 0; mt < 3; ++mt)
    #pragma unroll
    for (int j = 0; j < 8; ++j) acc[mt][j] = (floatx4){0.f, 0.f, 0.f, 0.f};

  for (int tap = 0; tap < 25; ++tap) {
    const int bufc = tap & 1;
    uint4 wpre;
    const bool pre = (tap < 24) && (tid < 192);
    if (pre) wpre = *(const uint4*)(wp + (tap + 1) * 1536 + tid * 8);
    const int ky = tap / 5, kx = tap - (tap / 5) * 5;
    const int tapoff = (ky * 36 + kx) * 32;
    const half_t* wb = &wlds[bufc][0][0];
    half8 A[3];
    #pragma unroll
    for (int mt = 0; mt < 3; ++mt)
      A[mt] = *(const half8*)(wb + mt * 512 + aoff);
    #pragma unroll
    for (int g = 0; g < 2; ++g) {
      half8 B[4];
      #pragma unroll
      for (int jj = 0; jj < 4; ++jj)
        B[jj] = *(const half8*)(&lin[0][0][0] + baseB[g * 4 + jj] + tapoff);
      #pragma unroll
      for (int mt = 0; mt < 3; ++mt)
        #pragma unroll
        for (int jj = 0; jj < 4; ++jj)
          acc[mt][g * 4 + jj] = __builtin_amdgcn_mfma_f32_16x16x32_f16(
              A[mt], B[jj], acc[mt][g * 4 + jj], 0, 0, 0);
    }
    if (pre) *(uint4*)(&wlds[1 - bufc][0][0] + tid * 8) = wpre;
    __syncthreads();
  }

  floatx4 bv[3];
  #pragma unroll
  for (int mt = 0; mt < 3; ++mt)
    #pragma unroll
    for (int r = 0; r < 4; ++r) {
      int oc = mt * 16 + q * 4 + r;
      bv[mt][r] = (oc < 40) ? bias[oc] : 0.f;
    }
  const bool act = ((nl & 3) == 0);
  #pragma unroll
  for (int j = 0; j < 8; ++j) {
    int nt = wv * 8 + j;
    int py = (ty0 >> 1) + (nt >> 2);
    int pc = (tx0 >> 1) + (nt & 3) * 4 + (nl >> 2);
    size_t pxbase = (((size_t)b * P2H + py) * P2W + pc) * 64;
    #pragma unroll
    for (int mt = 0; mt < 3; ++mt) {
      floatx4 v = acc[mt][j];
      PK4 pk;
      #pragma unroll
      for (int r = 0; r < 4; ++r) {
        float x = v[r];
        x = fmaxf(x, __shfl_xor(x, 1));
        x = fmaxf(x, __shfl_xor(x, 2));
        pk.h[r] = (half_t)fmaxf(x + bv[mt][r], 0.f);
      }
      if (act) *(uint2*)(P2 + pxbase + mt * 16 + q * 4) = pk.u;
    }
    if (act && q < 2)
      *(uint4*)(P2 + pxbase + 48 + q * 8) = make_uint4(0, 0, 0, 0);  // oc 48..63 = 0
  }
}

// ---------------- conv3 (40->20, 5x5) MFMA + relu -> X3 f16 NHWC32 ----------------
// conv tile 8x32 = 256 px (16 N-tiles); oc padded to 32 (2 M-tiles); K = 25 taps x 64c.
__global__ __launch_bounds__(256) void conv3_mfma(
    const half_t* __restrict__ P2, const half_t* __restrict__ wp,
    const float* __restrict__ bias, half_t* __restrict__ X3)
{
  __shared__ __align__(16) half_t lin[12][36][64];   // 55296 B
  __shared__ __align__(16) half_t wlds[2][32][64];   // 8192 B
  const int b = blockIdx.z, ty0 = blockIdx.y * 8, tx0 = blockIdx.x * 32;
  const int tid = threadIdx.x;
  for (int i = tid; i < 3456; i += 256) {
    int px = i >> 3, part = i & 7;
    int row = px / 36, col = px - row * 36;
    int gy = ty0 - 2 + row, gx = tx0 - 2 + col;
    uint4 v = make_uint4(0, 0, 0, 0);
    if (gy >= 0 && gy < P2H && gx >= 0 && gx < P2W)
      v = *(const uint4*)(P2 + (((size_t)b * P2H + gy) * P2W + gx) * 64 + part * 8);
    *(uint4*)&lin[row][col][part * 8] = v;
  }
  *(uint4*)(&wlds[0][0][0] + tid * 8) = *(const uint4*)(wp + tid * 8);
  __syncthreads();

  const int wv = tid >> 6, ln = tid & 63, q = ln >> 4, nl = ln & 15;
  int baseB[4];
  #pragma unroll
  for (int j = 0; j < 4; ++j) {
    int nt = wv * 4 + j;
    int ly = nt >> 1, lx = (nt & 1) * 16 + nl;
    baseB[j] = (ly * 36 + lx) * 64 + q * 8;
  }
  const int aoff = nl * 64 + q * 8;
  floatx4 acc[2][4];
  #pragma unroll
  for (int mt = 0; mt < 2; ++mt)
    #pragma unroll
    for (int j = 0; j < 4; ++j) acc[mt][j] = (floatx4){0.f, 0.f, 0.f, 0.f};

  for (int tap = 0; tap < 25; ++tap) {
    const int bufc = tap & 1;
    uint4 wpre;
    const bool pre = (tap < 24);
    if (pre) wpre = *(const uint4*)(wp + (tap + 1) * 2048 + tid * 8);
    const int ky = tap / 5, kx = tap - (tap / 5) * 5;
    const half_t* wb = &wlds[bufc][0][0];
    #pragma unroll
    for (int cb = 0; cb < 2; ++cb) {
      const int tapoff = (ky * 36 + kx) * 64 + cb * 32;
      half8 A[2];
      #pragma unroll
      for (int mt = 0; mt < 2; ++mt)
        A[mt] = *(const half8*)(wb + mt * 1024 + cb * 32 + aoff);
      half8 B[4];
      #pragma unroll
      for (int jj = 0; jj < 4; ++jj)
        B[jj] = *(const half8*)(&lin[0][0][0] + baseB[jj] + tapoff);
      #pragma unroll
      for (int mt = 0; mt < 2; ++mt)
        #pragma unroll
        for (int jj = 0; jj < 4; ++jj)
          acc[mt][jj] = __builtin_amdgcn_mfma_f32_16x16x32_f16(
              A[mt], B[jj], acc[mt][jj], 0, 0, 0);
    }
    if (pre) *(uint4*)(&wlds[1 - bufc][0][0] + tid * 8) = wpre;
    __syncthreads();
  }

  floatx4 bv[2];
  #pragma unroll
  for (int mt = 0; mt < 2; ++mt)
    #pragma unroll
    for (int r = 0; r < 4; ++r) {
      int oc = mt * 16 + q * 4 + r;
      bv[mt][r] = (oc < 20) ? bias[oc] : 0.f;
    }
  #pragma unroll
  for (int j = 0; j < 4; ++j) {
    int nt = wv * 4 + j;
    int y = ty0 + (nt >> 1), x = tx0 + (nt & 1) * 16 + nl;
    size_t pxbase = (((size_t)b * P2H + y) * P2W + x) * 32;
    #pragma unroll
    for (int mt = 0; mt < 2; ++mt) {
      floatx4 v = acc[mt][j];
      PK4 pk;
      #pragma unroll
      for (int r = 0; r < 4; ++r) pk.h[r] = (half_t)fmaxf(v[r] + bv[mt][r], 0.f);
      *(uint2*)(X3 + pxbase + mt * 16 + q * 4) = pk.u;
    }
  }
}

// ---------------- conv4 (20->10, 5x5) MFMA + relu -> X4 fp32 NHWC10 ----------------
// conv tile 16x32 = 512 px (32 N-tiles); oc padded to 16 (1 M-tile); K = 25 taps x 32c.
__global__ __launch_bounds__(256) void conv4_mfma(
    const half_t* __restrict__ X3, const half_t* __restrict__ wp,
    const float* __restrict__ bias, float* __restrict__ X4)
{
  __shared__ __align__(16) half_t lin[20][36][32];   // 46080 B
  __shared__ __align__(16) half_t wlds[2][16][32];   // 2048 B
  const int b = blockIdx.z, ty0 = blockIdx.y * 16, tx0 = blockIdx.x * 32;
  const int tid = threadIdx.x;
  for (int i = tid; i < 2880; i += 256) {
    int px = i >> 2, part = i & 3;
    int row = px / 36, col = px - row * 36;
    int gy = ty0 - 2 + row, gx = tx0 - 2 + col;
    uint4 v = make_uint4(0, 0, 0, 0);
    if (gy >= 0 && gy < P2H && gx >= 0 && gx < P2W)
      v = *(const uint4*)(X3 + (((size_t)b * P2H + gy) * P2W + gx) * 32 + part * 8);
    *(uint4*)&lin[row][col][part * 8] = v;
  }
  if (tid < 64)
    *(uint4*)(&wlds[0][0][0] + tid * 8) = *(const uint4*)(wp + tid * 8);
  __syncthreads();

  const int wv = tid >> 6, ln = tid & 63, q = ln >> 4, nl = ln & 15;
  int baseB[8];
  #pragma unroll
  for (int j = 0; j < 8; ++j) {
    int nt = wv * 8 + j;
    int ly = nt >> 1, lx = (nt & 1) * 16 + nl;
    baseB[j] = (ly * 36 + lx) * 32 + q * 8;
  }
  const int aoff = nl * 32 + q * 8;
  floatx4 acc[8];
  #pragma unroll
  for (int j = 0; j < 8; ++j) acc[j] = (floatx4){0.f, 0.f, 0.f, 0.f};

  for (int tap = 0; tap < 25; ++tap) {
    const int bufc = tap & 1;
    uint4 wpre;
    const bool pre = (tap < 24) && (tid < 64);
    if (pre) wpre = *(const uint4*)(wp + (tap + 1) * 512 + tid * 8);
    const int ky = tap / 5, kx = tap - (tap / 5) * 5;
    const int tapoff = (ky * 36 + kx) * 32;
    const half_t* wb = &wlds[bufc][0][0];
    half8 A = *(const half8*)(wb + aoff);
    #pragma unroll
    for (int j = 0; j < 8; ++j) {
      half8 B = *(const half8*)(&lin[0][0][0] + baseB[j] + tapoff);
      acc[j] = __builtin_amdgcn_mfma_f32_16x16x32_f16(A, B, acc[j], 0, 0, 0);
    }
    if (pre) *(uint4*)(&wlds[1 - bufc][0][0] + tid * 8) = wpre;
    __syncthreads();
  }

  float bv[4];
  #pragma unroll
  for (int r = 0; r < 4; ++r) {
    int oc = q * 4 + r;
    bv[r] = (oc < 10) ? bias[oc] : 0.f;
  }
  #pragma unroll
  for (int j = 0; j < 8; ++j) {
    int nt = wv * 8 + j;
    int y = ty0 + (nt >> 1), x = tx0 + (nt & 1) * 16 + nl;
    float* dst = X4 + (((size_t)b * P2H + y) * P2W + x) * 10;
    floatx4 v = acc[j];
    float r0 = fmaxf(v[0] + bv[0], 0.f), r1 = fmaxf(v[1] + bv[1], 0.f);
    float r2 = fmaxf(v[2] + bv[2], 0.f), r3 = fmaxf(v[3] + bv[3], 0.f);
    if (q < 2) {
      *(float2*)(dst + q * 4)     = make_float2(r0, r1);
      *(float2*)(dst + q * 4 + 2) = make_float2(r2, r3);
    } else if (q == 2) {
      *(float2*)(dst + 8) = make_float2(r0, r1);   // oc 8,9
    }
  }
}

// ---------------- conv5 (10->1, 1x1) + gray residual + relu ----------------
__global__ __launch_bounds__(256) void conv5_res(
    const float* __restrict__ X4, const float* __restrict__ w5,
    const float* __restrict__ b5, const float* __restrict__ in,
    float* __restrict__ out)
{
  const int idx = blockIdx.x * 256 + threadIdx.x;  // 0 .. 8*192*256-1
  const int j = idx & 255;
  const int bi = idx >> 8;
  const int i = bi % 192;
  const int b = bi / 192;
  const float* xp = X4 + (((size_t)b * P2H + i) * P2W + j) * 10;
  float sum = b5[0];
  #pragma unroll
  for (int c = 0; c < 10; ++c) sum += w5[c] * xp[c];
  const int r0 = 4 * i + 1, c0 = 4 * j + 1;
  float g = 0.f;
  #pragma unroll
  for (int ch = 0; ch < 3; ++ch) {
    const float coef = (ch == 0) ? 0.299f : ((ch == 1) ? 0.587f : 0.114f);
    const float* q = in + ((size_t)b * 3 + ch) * IN_H * IN_W;
    g += coef * (q[(size_t)r0 * IN_W + c0] + q[(size_t)r0 * IN_W + c0 + 1] +
                 q[(size_t)(r0 + 1) * IN_W + c0] + q[(size_t)(r0 + 1) * IN_W + c0 + 1]);
  }
  g *= 0.25f;
  out[idx] = fmaxf(sum + fmaxf(g, 0.f), 0.f);
}

extern "C" void kernel_launch(void* const* d_in, const int* in_sizes, int n_in,
                              void* d_out, int out_size, void* d_ws, size_t ws_size,
                              hipStream_t stream) {
  const float* input = (const float*)d_in[0];
  const float* w1 = (const float*)d_in[1];  const float* b1 = (const float*)d_in[2];
  const float* w2 = (const float*)d_in[3];  const float* b2 = (const float*)d_in[4];
  const float* w3 = (const float*)d_in[5];  const float* b3 = (const float*)d_in[6];
  const float* w4 = (const float*)d_in[7];  const float* b4 = (const float*)d_in[8];
  const float* w5 = (const float*)d_in[9];  const float* b5 = (const float*)d_in[10];
  float* out = (float*)d_out;
  char* ws = (char*)d_ws;

  half_t* P2h = (half_t*)(ws + OFF_P2);
  half_t* P1h = (half_t*)(ws + OFF_P1);
  half_t* X3h = (half_t*)(ws + OFF_X3);
  float*  X4f = (float*)(ws + OFF_X4);
  half_t* wp2 = (half_t*)(ws + OFF_W2);
  half_t* wp3 = (half_t*)(ws + OFF_W3);
  half_t* wp4 = (half_t*)(ws + OFF_W4);

  pack_weights<<<400, 256, 0, stream>>>(w2, w3, w4, wp2, wp3, wp4);
  conv1_pool<<<dim3(16, 96, 8), 256, 0, stream>>>(input, w1, b1, P1h);
  conv2_mfma<<<dim3(16, 24, 8), 256, 0, stream>>>(P1h, wp2, b2, P2h);
  conv3_mfma<<<dim3(8, 24, 8), 256, 0, stream>>>(P2h, wp3, b3, X3h);
  conv4_mfma<<<dim3(8, 12, 8), 256, 0, stream>>>(X3h, wp4, b4, X4f);
  conv5_res<<<1536, 256, 0, stream>>>(X4f, w5, b5, input, out);
}

// Round 3
// 508.209 us; speedup vs baseline: 3.5428x; 2.1185x over previous
//
#include <hip/hip_runtime.h>

// Res_MCNN_branch2 on gfx950 — all convs via f16 MFMA implicit-GEMM (16x16x32).
// conv1: K = kx*4+c (C=3 padded to 4, kx padded to 8), K-steps = 7 ky.
//        Weights (all taps, 14.3 KB) + input tile staged once -> barrier-free K-loop.
//        Fused relu+maxpool2 via shfl_xor -> P1 f16 NHWC32.
// conv2: K = 25 taps x 32c, fused relu+maxpool2 -> P2 f16 NHWC64.
// conv3: K = 25 taps x 64c -> X3 f16 NHWC32.
// conv4: K = 25 taps x 32c -> X4 fp32 NHWC10.
// conv5: 1x1 conv + gray residual (bilinear 4x == 2x2 avg at rows/cols {4i+1,4i+2}).

typedef _Float16 half_t;
typedef _Float16 half8 __attribute__((ext_vector_type(8)));
typedef float floatx4 __attribute__((ext_vector_type(4)));

#define IN_H 768
#define IN_W 1024
#define P1H 384
#define P1W 512
#define P2H 192
#define P2W 256

// workspace offsets (bytes)
#define OFF_P2 0ULL                 // f16 [8][192][256][64]  = 50,331,648
#define OFF_P1 50331648ULL          // f16 [8][384][512][32]  = 100,663,296
#define OFF_X3 50331648ULL          // reuse P1 region after conv2
#define OFF_X4 0ULL                 // fp32 [8][192][256][10] reuse P2 region after conv3
#define OFF_W2 150994944ULL         // f16 [25][48][32] = 76,800 el
#define OFF_W3 151072768ULL         // f16 [25][32][64] = 102,400 el
#define OFF_W4 151175168ULL         // f16 [25][16][32] = 25,600 el
#define OFF_W1 151226368ULL         // f16 [7][32][32]  = 7,168 el

union PK4 { half_t h[4]; uint2 u; };
union U8 { half8 v; uint2 u[2]; };

// ---------------- weight pre-pack (fp32 OIHW -> f16 packed) ----------------
__global__ __launch_bounds__(256) void pack_weights(
    const float* __restrict__ w2, const float* __restrict__ w3,
    const float* __restrict__ w4, const float* __restrict__ w1,
    half_t* __restrict__ wp2, half_t* __restrict__ wp3, half_t* __restrict__ wp4,
    half_t* __restrict__ wp1)
{
  int t = blockIdx.x * 256 + threadIdx.x;
  if (t < 38400) {                       // conv2: [25][48][32]
    int tap = t / 1536, r = t % 1536, oc = r >> 5, c = r & 31;
    float v = (oc < 40 && c < 20) ? w2[(oc * 20 + c) * 25 + tap] : 0.f;
    wp2[t] = (half_t)v;
  } else if (t < 89600) {                // conv3: [25][32][64]
    int u = t - 38400;
    int tap = u / 2048, r = u % 2048, oc = r >> 6, c = r & 63;
    float v = (oc < 20 && c < 40) ? w3[(oc * 40 + c) * 25 + tap] : 0.f;
    wp3[u] = (half_t)v;
  } else if (t < 102400) {               // conv4: [25][16][32]
    int u = t - 89600;
    int tap = u / 512, r = u % 512, oc = r >> 5, c = r & 31;
    float v = (oc < 10 && c < 20) ? w4[(oc * 20 + c) * 25 + tap] : 0.f;
    wp4[u] = (half_t)v;
  } else if (t < 109568) {               // conv1: [7][32][32], k = kx*4+c
    int u = t - 102400;
    int ky = u / 1024, r = u % 1024, oc = r >> 5, k = r & 31;
    int kx = k >> 2, c = k & 3;
    float v = (oc < 20 && c < 3 && kx < 7) ? w1[((oc * 3 + c) * 7 + ky) * 7 + kx] : 0.f;
    wp1[u] = (half_t)v;
  }
}

// ---------------- conv1 (3->20, 7x7, pad 3) MFMA + relu + pool -> P1 f16 NHWC32 ----------------
// conv tile 16x32 px (32 N-tiles of 16), oc padded to 32 (2 M-tiles).
// K mapping: k = kx*4 + c; one MFMA K-step per ky (7 steps, barrier-free).
// B-fragment (k=q*8..+7) = pixels (lx-3+2q, lx-2+2q) x 4c = 8 contiguous halves
// in the [row][col][4] LDS tile (8B aligned -> two ds_read_b64).
__global__ __launch_bounds__(256) void conv1_mfma(
    const float* __restrict__ in, const half_t* __restrict__ wp,
    const float* __restrict__ bias, half_t* __restrict__ P1)
{
  __shared__ __align__(16) half_t ltile[22 * 40 * 4];   // 7040 B, row stride 40 px
  __shared__ __align__(16) half_t wlds[7 * 32 * 32];    // 14336 B, all taps
  const int b = blockIdx.z, ty0 = blockIdx.y * 16, tx0 = blockIdx.x * 32;
  const int tid = threadIdx.x;

  for (int i = tid; i < 896; i += 256)
    *(uint4*)(wlds + i * 8) = *(const uint4*)(wp + i * 8);

  const float* p0 = in + (size_t)b * 3 * IN_H * IN_W;
  for (int i = tid; i < 880; i += 256) {          // 22 rows x 40 cols (38 real + 2 zero)
    int r = i / 40, c = i - r * 40;
    int gy = ty0 - 3 + r, gx = tx0 - 3 + c;
    float v0 = 0.f, v1 = 0.f, v2 = 0.f;
    if (c < 38 && gy >= 0 && gy < IN_H && gx >= 0 && gx < IN_W) {
      size_t o = (size_t)gy * IN_W + gx;
      v0 = p0[o];
      v1 = p0[o + IN_H * IN_W];
      v2 = p0[o + 2 * IN_H * IN_W];
    }
    PK4 pk;
    pk.h[0] = (half_t)v0; pk.h[1] = (half_t)v1;
    pk.h[2] = (half_t)v2; pk.h[3] = (half_t)0.f;
    *(uint2*)(ltile + (r * 40 + c) * 4) = pk.u;
  }
  __syncthreads();

  const int wv = tid >> 6, ln = tid & 63, q = ln >> 4, nl = ln & 15;
  // pixel mapping (same as conv2): pool partners in lanes xor 1 (x) / xor 2 (y)
  int baseB[8];
  #pragma unroll
  for (int j = 0; j < 8; ++j) {
    int nt = wv * 8 + j;
    int ly = (nt >> 2) * 2 + ((nl >> 1) & 1);
    int lx = (nt & 3) * 8 + (nl & 1) + ((nl >> 2) << 1);
    baseB[j] = (ly * 40 + lx + 2 * q) * 4;        // halves; +ky*160 per K-step
  }
  const int aoff = nl * 32 + q * 8;
  floatx4 acc[2][8];
  #pragma unroll
  for (int mt = 0; mt < 2; ++mt)
    #pragma unroll
    for (int j = 0; j < 8; ++j) acc[mt][j] = (floatx4){0.f, 0.f, 0.f, 0.f};

  for (int ky = 0; ky < 7; ++ky) {
    const half_t* wb = wlds + ky * 1024;
    half8 A0 = *(const half8*)(wb + aoff);
    half8 A1 = *(const half8*)(wb + 512 + aoff);
    const half_t* tb = ltile + ky * 160;
    #pragma unroll
    for (int j = 0; j < 8; ++j) {
      U8 B;
      B.u[0] = *(const uint2*)(tb + baseB[j]);
      B.u[1] = *(const uint2*)(tb + baseB[j] + 4);
      acc[0][j] = __builtin_amdgcn_mfma_f32_16x16x32_f16(A0, B.v, acc[0][j], 0, 0, 0);
      acc[1][j] = __builtin_amdgcn_mfma_f32_16x16x32_f16(A1, B.v, acc[1][j], 0, 0, 0);
    }
  }

  floatx4 bv[2];
  #pragma unroll
  for (int mt = 0; mt < 2; ++mt)
    #pragma unroll
    for (int r = 0; r < 4; ++r) {
      int oc = mt * 16 + q * 4 + r;
      bv[mt][r] = (oc < 20) ? bias[oc] : 0.f;
    }
  const bool act = ((nl & 3) == 0);
  #pragma unroll
  for (int j = 0; j < 8; ++j) {
    int nt = wv * 8 + j;
    int py = (ty0 >> 1) + (nt >> 2);
    int px = (tx0 >> 1) + (nt & 3) * 4 + (nl >> 2);
    size_t pxbase = (((size_t)b * P1H + py) * P1W + px) * 32;
    #pragma unroll
    for (int mt = 0; mt < 2; ++mt) {
      floatx4 v = acc[mt][j];
      PK4 pk;
      #pragma unroll
      for (int r = 0; r < 4; ++r) {
        float x = v[r];
        x = fmaxf(x, __shfl_xor(x, 1));
        x = fmaxf(x, __shfl_xor(x, 2));
        pk.h[r] = (half_t)fmaxf(x + bv[mt][r], 0.f);   // oc>=20: 0+0 -> 0 pad
      }
      if (act) *(uint2*)(P1 + pxbase + mt * 16 + q * 4) = pk.u;
    }
  }
}

// ---------------- conv2 (20->40, 5x5) MFMA + relu + pool -> P2 f16 NHWC64 ----------------
__global__ __launch_bounds__(256) void conv2_mfma(
    const half_t* __restrict__ P1, const half_t* __restrict__ wp,
    const float* __restrict__ bias, half_t* __restrict__ P2)
{
  __shared__ __align__(16) half_t lin[20][36][32];   // 46080 B
  __shared__ __align__(16) half_t wlds[2][48][32];   // 6144 B
  const int b = blockIdx.z, ty0 = blockIdx.y * 16, tx0 = blockIdx.x * 32;
  const int tid = threadIdx.x;
  for (int i = tid; i < 2880; i += 256) {
    int px = i >> 2, part = i & 3;
    int row = px / 36, col = px - row * 36;
    int gy = ty0 - 2 + row, gx = tx0 - 2 + col;
    uint4 v = make_uint4(0, 0, 0, 0);
    if (gy >= 0 && gy < P1H && gx >= 0 && gx < P1W)
      v = *(const uint4*)(P1 + (((size_t)b * P1H + gy) * P1W + gx) * 32 + part * 8);
    *(uint4*)&lin[row][col][part * 8] = v;
  }
  if (tid < 192)
    *(uint4*)(&wlds[0][0][0] + tid * 8) = *(const uint4*)(wp + tid * 8);
  __syncthreads();

  const int wv = tid >> 6, ln = tid & 63, q = ln >> 4, nl = ln & 15;
  int baseB[8];
  #pragma unroll
  for (int j = 0; j < 8; ++j) {
    int nt = wv * 8 + j;
    int ly = (nt >> 2) * 2 + ((nl >> 1) & 1);
    int lx = (nt & 3) * 8 + (nl & 1) + ((nl >> 2) << 1);
    baseB[j] = (ly * 36 + lx) * 32 + q * 8;
  }
  const int aoff = nl * 32 + q * 8;
  floatx4 acc[3][8];
  #pragma unroll
  for (int mt = 0; mt < 3; ++mt)
    #pragma unroll
    for (int j = 0; j < 8; ++j) acc[mt][j] = (floatx4){0.f, 0.f, 0.f, 0.f};

  for (int tap = 0; tap < 25; ++tap) {
    const int bufc = tap & 1;
    uint4 wpre;
    const bool pre = (tap < 24) && (tid < 192);
    if (pre) wpre = *(const uint4*)(wp + (tap + 1) * 1536 + tid * 8);
    const int ky = tap / 5, kx = tap - (tap / 5) * 5;
    const int tapoff = (ky * 36 + kx) * 32;
    const half_t* wb = &wlds[bufc][0][0];
    half8 A[3];
    #pragma unroll
    for (int mt = 0; mt < 3; ++mt)
      A[mt] = *(const half8*)(wb + mt * 512 + aoff);
    #pragma unroll
    for (int g = 0; g < 2; ++g) {
      half8 B[4];
      #pragma unroll
      for (int jj = 0; jj < 4; ++jj)
        B[jj] = *(const half8*)(&lin[0][0][0] + baseB[g * 4 + jj] + tapoff);
      #pragma unroll
      for (int mt = 0; mt < 3; ++mt)
        #pragma unroll
        for (int jj = 0; jj < 4; ++jj)
          acc[mt][g * 4 + jj] = __builtin_amdgcn_mfma_f32_16x16x32_f16(
              A[mt], B[jj], acc[mt][g * 4 + jj], 0, 0, 0);
    }
    if (pre) *(uint4*)(&wlds[1 - bufc][0][0] + tid * 8) = wpre;
    __syncthreads();
  }

  floatx4 bv[3];
  #pragma unroll
  for (int mt = 0; mt < 3; ++mt)
    #pragma unroll
    for (int r = 0; r < 4; ++r) {
      int oc = mt * 16 + q * 4 + r;
      bv[mt][r] = (oc < 40) ? bias[oc] : 0.f;
    }
  const bool act = ((nl & 3) == 0);
  #pragma unroll
  for (int j = 0; j < 8; ++j) {
    int nt = wv * 8 + j;
    int py = (ty0 >> 1) + (nt >> 2);
    int pc = (tx0 >> 1) + (nt & 3) * 4 + (nl >> 2);
    size_t pxbase = (((size_t)b * P2H + py) * P2W + pc) * 64;
    #pragma unroll
    for (int mt = 0; mt < 3; ++mt) {
      floatx4 v = acc[mt][j];
      PK4 pk;
      #pragma unroll
      for (int r = 0; r < 4; ++r) {
        float x = v[r];
        x = fmaxf(x, __shfl_xor(x, 1));
        x = fmaxf(x, __shfl_xor(x, 2));
        pk.h[r] = (half_t)fmaxf(x + bv[mt][r], 0.f);
      }
      if (act) *(uint2*)(P2 + pxbase + mt * 16 + q * 4) = pk.u;
    }
    if (act && q < 2)
      *(uint4*)(P2 + pxbase + 48 + q * 8) = make_uint4(0, 0, 0, 0);  // oc 48..63 = 0
  }
}

// ---------------- conv3 (40->20, 5x5) MFMA + relu -> X3 f16 NHWC32 ----------------
__global__ __launch_bounds__(256) void conv3_mfma(
    const half_t* __restrict__ P2, const half_t* __restrict__ wp,
    const float* __restrict__ bias, half_t* __restrict__ X3)
{
  __shared__ __align__(16) half_t lin[12][36][64];   // 55296 B
  __shared__ __align__(16) half_t wlds[2][32][64];   // 8192 B
  const int b = blockIdx.z, ty0 = blockIdx.y * 8, tx0 = blockIdx.x * 32;
  const int tid = threadIdx.x;
  for (int i = tid; i < 3456; i += 256) {
    int px = i >> 3, part = i & 7;
    int row = px / 36, col = px - row * 36;
    int gy = ty0 - 2 + row, gx = tx0 - 2 + col;
    uint4 v = make_uint4(0, 0, 0, 0);
    if (gy >= 0 && gy < P2H && gx >= 0 && gx < P2W)
      v = *(const uint4*)(P2 + (((size_t)b * P2H + gy) * P2W + gx) * 64 + part * 8);
    *(uint4*)&lin[row][col][part * 8] = v;
  }
  *(uint4*)(&wlds[0][0][0] + tid * 8) = *(const uint4*)(wp + tid * 8);
  __syncthreads();

  const int wv = tid >> 6, ln = tid & 63, q = ln >> 4, nl = ln & 15;
  int baseB[4];
  #pragma unroll
  for (int j = 0; j < 4; ++j) {
    int nt = wv * 4 + j;
    int ly = nt >> 1, lx = (nt & 1) * 16 + nl;
    baseB[j] = (ly * 36 + lx) * 64 + q * 8;
  }
  const int aoff = nl * 64 + q * 8;
  floatx4 acc[2][4];
  #pragma unroll
  for (int mt = 0; mt < 2; ++mt)
    #pragma unroll
    for (int j = 0; j < 4; ++j) acc[mt][j] = (floatx4){0.f, 0.f, 0.f, 0.f};

  for (int tap = 0; tap < 25; ++tap) {
    const int bufc = tap & 1;
    uint4 wpre;
    const bool pre = (tap < 24);
    if (pre) wpre = *(const uint4*)(wp + (tap + 1) * 2048 + tid * 8);
    const int ky = tap / 5, kx = tap - (tap / 5) * 5;
    const half_t* wb = &wlds[bufc][0][0];
    #pragma unroll
    for (int cb = 0; cb < 2; ++cb) {
      const int tapoff = (ky * 36 + kx) * 64 + cb * 32;
      half8 A[2];
      #pragma unroll
      for (int mt = 0; mt < 2; ++mt)
        A[mt] = *(const half8*)(wb + mt * 1024 + cb * 32 + aoff);
      half8 B[4];
      #pragma unroll
      for (int jj = 0; jj < 4; ++jj)
        B[jj] = *(const half8*)(&lin[0][0][0] + baseB[jj] + tapoff);
      #pragma unroll
      for (int mt = 0; mt < 2; ++mt)
        #pragma unroll
        for (int jj = 0; jj < 4; ++jj)
          acc[mt][jj] = __builtin_amdgcn_mfma_f32_16x16x32_f16(
              A[mt], B[jj], acc[mt][jj], 0, 0, 0);
    }
    if (pre) *(uint4*)(&wlds[1 - bufc][0][0] + tid * 8) = wpre;
    __syncthreads();
  }

  floatx4 bv[2];
  #pragma unroll
  for (int mt = 0; mt < 2; ++mt)
    #pragma unroll
    for (int r = 0; r < 4; ++r) {
      int oc = mt * 16 + q * 4 + r;
      bv[mt][r] = (oc < 20) ? bias[oc] : 0.f;
    }
  #pragma unroll
  for (int j = 0; j < 4; ++j) {
    int nt = wv * 4 + j;
    int y = ty0 + (nt >> 1), x = tx0 + (nt & 1) * 16 + nl;
    size_t pxbase = (((size_t)b * P2H + y) * P2W + x) * 32;
    #pragma unroll
    for (int mt = 0; mt < 2; ++mt) {
      floatx4 v = acc[mt][j];
      PK4 pk;
      #pragma unroll
      for (int r = 0; r < 4; ++r) pk.h[r] = (half_t)fmaxf(v[r] + bv[mt][r], 0.f);
      *(uint2*)(X3 + pxbase + mt * 16 + q * 4) = pk.u;
    }
  }
}

// ---------------- conv4 (20->10, 5x5) MFMA + relu -> X4 fp32 NHWC10 ----------------
__global__ __launch_bounds__(256) void conv4_mfma(
    const half_t* __restrict__ X3, const half_t* __restrict__ wp,
    const float* __restrict__ bias, float* __restrict__ X4)
{
  __shared__ __align__(16) half_t lin[20][36][32];   // 46080 B
  __shared__ __align__(16) half_t wlds[2][16][32];   // 2048 B
  const int b = blockIdx.z, ty0 = blockIdx.y * 16, tx0 = blockIdx.x * 32;
  const int tid = threadIdx.x;
  for (int i = tid; i < 2880; i += 256) {
    int px = i >> 2, part = i & 3;
    int row = px / 36, col = px - row * 36;
    int gy = ty0 - 2 + row, gx = tx0 - 2 + col;
    uint4 v = make_uint4(0, 0, 0, 0);
    if (gy >= 0 && gy < P2H && gx >= 0 && gx < P2W)
      v = *(const uint4*)(X3 + (((size_t)b * P2H + gy) * P2W + gx) * 32 + part * 8);
    *(uint4*)&lin[row][col][part * 8] = v;
  }
  if (tid < 64)
    *(uint4*)(&wlds[0][0][0] + tid * 8) = *(const uint4*)(wp + tid * 8);
  __syncthreads();

  const int wv = tid >> 6, ln = tid & 63, q = ln >> 4, nl = ln & 15;
  int baseB[8];
  #pragma unroll
  for (int j = 0; j < 8; ++j) {
    int nt = wv * 8 + j;
    int ly = nt >> 1, lx = (nt & 1) * 16 + nl;
    baseB[j] = (ly * 36 + lx) * 32 + q * 8;
  }
  const int aoff = nl * 32 + q * 8;
  floatx4 acc[8];
  #pragma unroll
  for (int j = 0; j < 8; ++j) acc[j] = (floatx4){0.f, 0.f, 0.f, 0.f};

  for (int tap = 0; tap < 25; ++tap) {
    const int bufc = tap & 1;
    uint4 wpre;
    const bool pre = (tap < 24) && (tid < 64);
    if (pre) wpre = *(const uint4*)(wp + (tap + 1) * 512 + tid * 8);
    const int ky = tap / 5, kx = tap - (tap / 5) * 5;
    const int tapoff = (ky * 36 + kx) * 32;
    const half_t* wb = &wlds[bufc][0][0];
    half8 A = *(const half8*)(wb + aoff);
    #pragma unroll
    for (int j = 0; j < 8; ++j) {
      half8 B = *(const half8*)(&lin[0][0][0] + baseB[j] + tapoff);
      acc[j] = __builtin_amdgcn_mfma_f32_16x16x32_f16(A, B, acc[j], 0, 0, 0);
    }
    if (pre) *(uint4*)(&wlds[1 - bufc][0][0] + tid * 8) = wpre;
    __syncthreads();
  }

  float bv[4];
  #pragma unroll
  for (int r = 0; r < 4; ++r) {
    int oc = q * 4 + r;
    bv[r] = (oc < 10) ? bias[oc] : 0.f;
  }
  #pragma unroll
  for (int j = 0; j < 8; ++j) {
    int nt = wv * 8 + j;
    int y = ty0 + (nt >> 1), x = tx0 + (nt & 1) * 16 + nl;
    float* dst = X4 + (((size_t)b * P2H + y) * P2W + x) * 10;
    floatx4 v = acc[j];
    float r0 = fmaxf(v[0] + bv[0], 0.f), r1 = fmaxf(v[1] + bv[1], 0.f);
    float r2 = fmaxf(v[2] + bv[2], 0.f), r3 = fmaxf(v[3] + bv[3], 0.f);
    if (q < 2) {
      *(float2*)(dst + q * 4)     = make_float2(r0, r1);
      *(float2*)(dst + q * 4 + 2) = make_float2(r2, r3);
    } else if (q == 2) {
      *(float2*)(dst + 8) = make_float2(r0, r1);   // oc 8,9
    }
  }
}

// ---------------- conv5 (10->1, 1x1) + gray residual + relu ----------------
__global__ __launch_bounds__(256) void conv5_res(
    const float* __restrict__ X4, const float* __restrict__ w5,
    const float* __restrict__ b5, const float* __restrict__ in,
    float* __restrict__ out)
{
  const int idx = blockIdx.x * 256 + threadIdx.x;  // 0 .. 8*192*256-1
  const int j = idx & 255;
  const int bi = idx >> 8;
  const int i = bi % 192;
  const int b = bi / 192;
  const float* xp = X4 + (((size_t)b * P2H + i) * P2W + j) * 10;
  float sum = b5[0];
  #pragma unroll
  for (int c = 0; c < 10; ++c) sum += w5[c] * xp[c];
  const int r0 = 4 * i + 1, c0 = 4 * j + 1;
  float g = 0.f;
  #pragma unroll
  for (int ch = 0; ch < 3; ++ch) {
    const float coef = (ch == 0) ? 0.299f : ((ch == 1) ? 0.587f : 0.114f);
    const float* q = in + ((size_t)b * 3 + ch) * IN_H * IN_W;
    g += coef * (q[(size_t)r0 * IN_W + c0] + q[(size_t)r0 * IN_W + c0 + 1] +
                 q[(size_t)(r0 + 1) * IN_W + c0] + q[(size_t)(r0 + 1) * IN_W + c0 + 1]);
  }
  g *= 0.25f;
  out[idx] = fmaxf(sum + fmaxf(g, 0.f), 0.f);
}

extern "C" void kernel_launch(void* const* d_in, const int* in_sizes, int n_in,
                              void* d_out, int out_size, void* d_ws, size_t ws_size,
                              hipStream_t stream) {
  const float* input = (const float*)d_in[0];
  const float* w1 = (const float*)d_in[1];  const float* b1 = (const float*)d_in[2];
  const float* w2 = (const float*)d_in[3];  const float* b2 = (const float*)d_in[4];
  const float* w3 = (const float*)d_in[5];  const float* b3 = (const float*)d_in[6];
  const float* w4 = (const float*)d_in[7];  const float* b4 = (const float*)d_in[8];
  const float* w5 = (const float*)d_in[9];  const float* b5 = (const float*)d_in[10];
  float* out = (float*)d_out;
  char* ws = (char*)d_ws;

  half_t* P2h = (half_t*)(ws + OFF_P2);
  half_t* P1h = (half_t*)(ws + OFF_P1);
  half_t* X3h = (half_t*)(ws + OFF_X3);
  float*  X4f = (float*)(ws + OFF_X4);
  half_t* wp2 = (half_t*)(ws + OFF_W2);
  half_t* wp3 = (half_t*)(ws + OFF_W3);
  half_t* wp4 = (half_t*)(ws + OFF_W4);
  half_t* wp1 = (half_t*)(ws + OFF_W1);

  pack_weights<<<432, 256, 0, stream>>>(w2, w3, w4, w1, wp2, wp3, wp4, wp1);
  conv1_mfma<<<dim3(32, 48, 8), 256, 0, stream>>>(input, wp1, b1, P1h);
  conv2_mfma<<<dim3(16, 24, 8), 256, 0, stream>>>(P1h, wp2, b2, P2h);
  conv3_mfma<<<dim3(8, 24, 8), 256, 0, stream>>>(P2h, wp3, b3, X3h);
  conv4_mfma<<<dim3(8, 12, 8), 256, 0, stream>>>(X3h, wp4, b4, X4f);
  conv5_res<<<1536, 256, 0, stream>>>(X4f, w5, b5, input, out);
}